// Round 1
// baseline (872.366 us; speedup 1.0000x reference)
//
#include <hip/hip_runtime.h>

#define L_SEQ 2048
#define NDIM 2048
#define DINNER 2048
#define NSTATE 32
#define BSZ 4
#define DTR 64
#define NROWS (BSZ * L_SEQ)  // 8192

// ---------------- Kernel 1: deltaBC = x @ W_bc^T ----------------
// M=8192, N=128, K=2048. BM=32, BN=128, BK=32, 256 threads, 4x4 micro-tile.
__global__ __launch_bounds__(256) void k_dbc(const float* __restrict__ x,
                                             const float* __restrict__ Wbc,
                                             float* __restrict__ dbc) {
  __shared__ float xs[32][36];    // [row][k], padded, fp32
  __shared__ float ws[32][132];   // [k][col], padded
  const int tid = threadIdx.x;
  const int tx = tid & 31;        // col tile (4 cols each)
  const int ty = tid >> 5;        // row tile (4 rows each)
  const int row0 = blockIdx.x * 32;

  float acc[4][4];
#pragma unroll
  for (int i = 0; i < 4; ++i)
#pragma unroll
    for (int j = 0; j < 4; ++j) acc[i][j] = 0.f;

  for (int kb = 0; kb < NDIM; kb += 32) {
    // x tile: 32 rows x 32 k (one float4 per thread)
    {
      const int r = tid >> 3;
      const int k0 = (tid & 7) * 4;
      const float4 v = *(const float4*)(x + (size_t)(row0 + r) * NDIM + kb + k0);
      *(float4*)&xs[r][k0] = v;
    }
    // W tile: ws[k][col] = Wbc[col][kb+k]
    {
      const int col = tid & 127;
      const int k0 = (tid >> 7) * 16;
#pragma unroll
      for (int j = 0; j < 4; ++j) {
        const float4 v = *(const float4*)(Wbc + (size_t)col * NDIM + kb + k0 + j * 4);
        ws[k0 + j * 4 + 0][col] = v.x;
        ws[k0 + j * 4 + 1][col] = v.y;
        ws[k0 + j * 4 + 2][col] = v.z;
        ws[k0 + j * 4 + 3][col] = v.w;
      }
    }
    __syncthreads();

#pragma unroll
    for (int k = 0; k < 32; k += 4) {
      float a_[4][4];
#pragma unroll
      for (int i = 0; i < 4; ++i) {
        const float4 av = *(const float4*)&xs[ty * 4 + i][k];
        a_[i][0] = av.x; a_[i][1] = av.y; a_[i][2] = av.z; a_[i][3] = av.w;
      }
#pragma unroll
      for (int kk = 0; kk < 4; ++kk) {
        const float4 bv = *(const float4*)&ws[k + kk][tx * 4];
        float b_[4] = {bv.x, bv.y, bv.z, bv.w};
#pragma unroll
        for (int i = 0; i < 4; ++i)
#pragma unroll
          for (int j = 0; j < 4; ++j)
            acc[i][j] = fmaf(a_[i][kk], b_[j], acc[i][j]);
      }
    }
    __syncthreads();
  }

#pragma unroll
  for (int i = 0; i < 4; ++i) {
    float4 o = {acc[i][0], acc[i][1], acc[i][2], acc[i][3]};
    *(float4*)(dbc + (size_t)(row0 + ty * 4 + i) * 128 + tx * 4) = o;
  }
}

// ------- Kernel 2: delta = softplus(dt_r @ W_dt^T + b_dt) -> d_out -------
// M=8192, N=2048, K=64. Block: 16 rows x 128 cols, 256 threads, 2x4 micro.
__global__ __launch_bounds__(256) void k_dt(const float* __restrict__ dbc,
                                            const float* __restrict__ Wdt,
                                            const float* __restrict__ bdt,
                                            float* dy) {
  __shared__ float asn[16][68];   // [row][k] padded (68*4=272B, 16B aligned)
  __shared__ float wst[64][132];  // [k][col] padded
  const int tid = threadIdx.x;
  const int tx = tid & 31;        // 4 cols each
  const int ty = tid >> 5;        // 2 rows each
  const int row0 = blockIdx.y * 16;
  const int col0 = blockIdx.x * 128;

  // a tile: 16 rows x 64 k
  {
    const int r = tid >> 4;
    const int k0 = (tid & 15) * 4;
    const float4 v = *(const float4*)(dbc + (size_t)(row0 + r) * 128 + k0);
    *(float4*)&asn[r][k0] = v;
  }
  // W tile: wst[k][col] = Wdt[col0+col][k]
  {
    const int col = tid & 127;
    const int k0 = (tid >> 7) * 32;
#pragma unroll
    for (int j = 0; j < 8; ++j) {
      const float4 v = *(const float4*)(Wdt + (size_t)(col0 + col) * 64 + k0 + j * 4);
      wst[k0 + j * 4 + 0][col] = v.x;
      wst[k0 + j * 4 + 1][col] = v.y;
      wst[k0 + j * 4 + 2][col] = v.z;
      wst[k0 + j * 4 + 3][col] = v.w;
    }
  }
  __syncthreads();

  float acc[2][4];
#pragma unroll
  for (int i = 0; i < 2; ++i)
#pragma unroll
    for (int j = 0; j < 4; ++j) acc[i][j] = 0.f;

#pragma unroll
  for (int k = 0; k < 64; k += 4) {
    float a_[2][4];
#pragma unroll
    for (int i = 0; i < 2; ++i) {
      const float4 av = *(const float4*)&asn[ty * 2 + i][k];
      a_[i][0] = av.x; a_[i][1] = av.y; a_[i][2] = av.z; a_[i][3] = av.w;
    }
#pragma unroll
    for (int kk = 0; kk < 4; ++kk) {
      const float4 bv = *(const float4*)&wst[k + kk][tx * 4];
      float b_[4] = {bv.x, bv.y, bv.z, bv.w};
#pragma unroll
      for (int i = 0; i < 2; ++i)
#pragma unroll
        for (int j = 0; j < 4; ++j)
          acc[i][j] = fmaf(a_[i][kk], b_[j], acc[i][j]);
    }
  }

  const int c = col0 + tx * 4;
  const float4 bb = *(const float4*)(bdt + c);
  const float bias[4] = {bb.x, bb.y, bb.z, bb.w};
#pragma unroll
  for (int i = 0; i < 2; ++i) {
    float o[4];
#pragma unroll
    for (int j = 0; j < 4; ++j) {
      const float v = acc[i][j] + bias[j];
      o[j] = (v > 20.f) ? v : __logf(1.f + __expf(v));
    }
    float4 ov = {o[0], o[1], o[2], o[3]};
    *(float4*)(dy + (size_t)(row0 + ty * 2 + i) * DINNER + c) = ov;
  }
}

// ---------------- Kernel 3: selective scan ----------------
// lane = state n (32 per channel), 2 channels per wave, 1024-thread blocks.
// Reads delta from dy (d_out) and overwrites with y (read-before-write per loc).
template <int CTRL>
__device__ __forceinline__ float dpp_mov(float v) {
  return __int_as_float(
      __builtin_amdgcn_update_dpp(0, __float_as_int(v), CTRL, 0xF, 0xF, true));
}

__global__ __launch_bounds__(1024) void k_scan(const float* __restrict__ x,
                                               const float* __restrict__ dbc,
                                               const float* __restrict__ Alog,
                                               const float* __restrict__ Dpar,
                                               float* dy) {
  const int g = blockIdx.x * 1024 + threadIdx.x;
  const int n = g & 31;
  const int ch = g >> 5;
  const int d = ch & (DINNER - 1);
  const int b = ch >> 11;

  const float An = -__expf(Alog[d * NSTATE + n]);
  const float Dd = Dpar[d];

  unsigned xd = (unsigned)(b * L_SEQ) * DINNER + d;  // elem idx of (b, t=0, d)
  unsigned bc = (unsigned)(b * L_SEQ) * 128 + 64 + n;

  float dlt = dy[xd];
  float u = x[xd];
  float bv = dbc[bc];
  float cv = dbc[bc + 32];
  float h = 0.f;

  for (int t = 0; t < L_SEQ; ++t) {
    float nd = 0.f, nu = 0.f, nb = 0.f, nc = 0.f;
    if (t < L_SEQ - 1) {  // prefetch t+1
      nd = dy[xd + DINNER];
      nu = x[xd + DINNER];
      nb = dbc[bc + 128];
      nc = dbc[bc + 160];
    }
    const float dA = __expf(dlt * An);
    const float dBu = dlt * u * bv;
    h = fmaf(dA, h, dBu);
    float p = h * cv;
    // sum over 32 lanes: 4 DPP adds + 1 swizzle(xor16)
    p += dpp_mov<0xB1>(p);   // quad_perm xor1
    p += dpp_mov<0x4E>(p);   // quad_perm xor2
    p += dpp_mov<0x141>(p);  // row_half_mirror (xor-4 equivalent)
    p += dpp_mov<0x140>(p);  // row_mirror (xor-8 equivalent)
    p += __int_as_float(
        __builtin_amdgcn_ds_swizzle(__float_as_int(p), 0x401F));  // xor16
    if (n == 0) dy[xd] = fmaf(u, Dd, p);
    dlt = nd; u = nu; bv = nb; cv = nc;
    xd += DINNER;
    bc += 128;
  }
}

extern "C" void kernel_launch(void* const* d_in, const int* in_sizes, int n_in,
                              void* d_out, int out_size, void* d_ws, size_t ws_size,
                              hipStream_t stream) {
  const float* x    = (const float*)d_in[0];
  // d_in[1] = z (unused by reference)
  const float* Wbc  = (const float*)d_in[2];
  const float* Wdt  = (const float*)d_in[3];
  const float* bdt  = (const float*)d_in[4];
  const float* Alog = (const float*)d_in[5];
  const float* Dpar = (const float*)d_in[6];
  float* dy  = (float*)d_out;
  float* dbc = (float*)d_ws;  // 8192*128 f32 = 4 MB

  hipLaunchKernelGGL(k_dbc, dim3(NROWS / 32), dim3(256), 0, stream, x, Wbc, dbc);
  hipLaunchKernelGGL(k_dt, dim3(DINNER / 128, NROWS / 16), dim3(256), 0, stream,
                     dbc, Wdt, bdt, dy);
  hipLaunchKernelGGL(k_scan, dim3(BSZ * DINNER * NSTATE / 1024), dim3(1024), 0,
                     stream, x, dbc, Alog, Dpar, dy);
}

// Round 2
// 434.072 us; speedup vs baseline: 2.0097x; 2.0097x over previous
//
#include <hip/hip_runtime.h>

#define L_SEQ 2048
#define NDIM 2048
#define DINNER 2048
#define NSTATE 32
#define BSZ 4
#define DTR 64
#define NROWS (BSZ * L_SEQ)  // 8192
#define TCH 32               // timesteps per scan chunk

// ---------------- Kernel 1: deltaBC = x @ W_bc^T ----------------
__global__ __launch_bounds__(256) void k_dbc(const float* __restrict__ x,
                                             const float* __restrict__ Wbc,
                                             float* __restrict__ dbc) {
  __shared__ float xs[32][36];
  __shared__ float ws[32][132];
  const int tid = threadIdx.x;
  const int tx = tid & 31;
  const int ty = tid >> 5;
  const int row0 = blockIdx.x * 32;

  float acc[4][4];
#pragma unroll
  for (int i = 0; i < 4; ++i)
#pragma unroll
    for (int j = 0; j < 4; ++j) acc[i][j] = 0.f;

  for (int kb = 0; kb < NDIM; kb += 32) {
    {
      const int r = tid >> 3;
      const int k0 = (tid & 7) * 4;
      const float4 v = *(const float4*)(x + (size_t)(row0 + r) * NDIM + kb + k0);
      *(float4*)&xs[r][k0] = v;
    }
    {
      const int col = tid & 127;
      const int k0 = (tid >> 7) * 16;
#pragma unroll
      for (int j = 0; j < 4; ++j) {
        const float4 v = *(const float4*)(Wbc + (size_t)col * NDIM + kb + k0 + j * 4);
        ws[k0 + j * 4 + 0][col] = v.x;
        ws[k0 + j * 4 + 1][col] = v.y;
        ws[k0 + j * 4 + 2][col] = v.z;
        ws[k0 + j * 4 + 3][col] = v.w;
      }
    }
    __syncthreads();

#pragma unroll
    for (int k = 0; k < 32; k += 4) {
      float a_[4][4];
#pragma unroll
      for (int i = 0; i < 4; ++i) {
        const float4 av = *(const float4*)&xs[ty * 4 + i][k];
        a_[i][0] = av.x; a_[i][1] = av.y; a_[i][2] = av.z; a_[i][3] = av.w;
      }
#pragma unroll
      for (int kk = 0; kk < 4; ++kk) {
        const float4 bv = *(const float4*)&ws[k + kk][tx * 4];
        float b_[4] = {bv.x, bv.y, bv.z, bv.w};
#pragma unroll
        for (int i = 0; i < 4; ++i)
#pragma unroll
          for (int j = 0; j < 4; ++j)
            acc[i][j] = fmaf(a_[i][kk], b_[j], acc[i][j]);
      }
    }
    __syncthreads();
  }

#pragma unroll
  for (int i = 0; i < 4; ++i) {
    float4 o = {acc[i][0], acc[i][1], acc[i][2], acc[i][3]};
    *(float4*)(dbc + (size_t)(row0 + ty * 4 + i) * 128 + tx * 4) = o;
  }
}

// ------- Kernel 2: delta = softplus(dt_r @ W_dt^T + b_dt) -> d_out -------
__global__ __launch_bounds__(256) void k_dt(const float* __restrict__ dbc,
                                            const float* __restrict__ Wdt,
                                            const float* __restrict__ bdt,
                                            float* dy) {
  __shared__ float asn[16][68];
  __shared__ float wst[64][132];
  const int tid = threadIdx.x;
  const int tx = tid & 31;
  const int ty = tid >> 5;
  const int row0 = blockIdx.y * 16;
  const int col0 = blockIdx.x * 128;

  {
    const int r = tid >> 4;
    const int k0 = (tid & 15) * 4;
    const float4 v = *(const float4*)(dbc + (size_t)(row0 + r) * 128 + k0);
    *(float4*)&asn[r][k0] = v;
  }
  {
    const int col = tid & 127;
    const int k0 = (tid >> 7) * 32;
#pragma unroll
    for (int j = 0; j < 8; ++j) {
      const float4 v = *(const float4*)(Wdt + (size_t)(col0 + col) * 64 + k0 + j * 4);
      wst[k0 + j * 4 + 0][col] = v.x;
      wst[k0 + j * 4 + 1][col] = v.y;
      wst[k0 + j * 4 + 2][col] = v.z;
      wst[k0 + j * 4 + 3][col] = v.w;
    }
  }
  __syncthreads();

  float acc[2][4];
#pragma unroll
  for (int i = 0; i < 2; ++i)
#pragma unroll
    for (int j = 0; j < 4; ++j) acc[i][j] = 0.f;

#pragma unroll
  for (int k = 0; k < 64; k += 4) {
    float a_[2][4];
#pragma unroll
    for (int i = 0; i < 2; ++i) {
      const float4 av = *(const float4*)&asn[ty * 2 + i][k];
      a_[i][0] = av.x; a_[i][1] = av.y; a_[i][2] = av.z; a_[i][3] = av.w;
    }
#pragma unroll
    for (int kk = 0; kk < 4; ++kk) {
      const float4 bv = *(const float4*)&wst[k + kk][tx * 4];
      float b_[4] = {bv.x, bv.y, bv.z, bv.w};
#pragma unroll
      for (int i = 0; i < 2; ++i)
#pragma unroll
        for (int j = 0; j < 4; ++j)
          acc[i][j] = fmaf(a_[i][kk], b_[j], acc[i][j]);
    }
  }

  const int c = col0 + tx * 4;
  const float4 bb = *(const float4*)(bdt + c);
  const float bias[4] = {bb.x, bb.y, bb.z, bb.w};
#pragma unroll
  for (int i = 0; i < 2; ++i) {
    float o[4];
#pragma unroll
    for (int j = 0; j < 4; ++j) {
      const float v = acc[i][j] + bias[j];
      o[j] = (v > 20.f) ? v : __logf(1.f + __expf(v));
    }
    float4 ov = {o[0], o[1], o[2], o[3]};
    *(float4*)(dy + (size_t)(row0 + ty * 2 + i) * DINNER + c) = ov;
  }
}

// ---------------- Kernel 3: selective scan (chunked LDS staging) ----------
template <int CTRL>
__device__ __forceinline__ float dpp_mov(float v) {
  return __int_as_float(
      __builtin_amdgcn_update_dpp(0, __float_as_int(v), CTRL, 0xF, 0xF, true));
}

__device__ __forceinline__ float red32(float p) {
  p += dpp_mov<0xB1>(p);   // xor1 (quad_perm)
  p += dpp_mov<0x4E>(p);   // xor2 (quad_perm)
  p += dpp_mov<0x141>(p);  // xor4 (row_half_mirror)
  p += dpp_mov<0x140>(p);  // xor8 (row_mirror)
  p += __int_as_float(
      __builtin_amdgcn_ds_swizzle(__float_as_int(p), 0x401F));  // xor16
  return p;
}

// Block: 1024 threads = 32 channel-groups of 32 state-lanes; one b, 32 d's.
// Per chunk of 32 t: cooperative coalesced staging of {delta,u} and {B,C}
// into double-buffered LDS, then 32 inner iters of pure LDS+VALU.
__global__ __launch_bounds__(1024) void k_scan(const float* __restrict__ x,
                                               const float* __restrict__ dbc,
                                               const float* __restrict__ Alog,
                                               const float* __restrict__ Dpar,
                                               float* dy) {
  __shared__ float sDU[2][TCH][32][2];  // [buf][t][channel][{delta,u}]
  __shared__ float sBC[2][TCH][32][2];  // [buf][t][state][{B,C}]
  __shared__ float sY[TCH][33];         // padded transpose buffer

  const int tid = threadIdx.x;
  const int nn = tid & 31;   // state lane within group / column in staging
  const int grp = tid >> 5;  // channel within block / t-local in staging
  const int b = blockIdx.x >> 6;
  const int d0 = (blockIdx.x & 63) * 32;
  const int d = d0 + grp;

  const float An = -__expf(Alog[(size_t)d * NSTATE + nn]);
  const float Dd = Dpar[d];

  const size_t rowX0 = (size_t)b * L_SEQ * DINNER + d0 + nn;  // stride DINNER
  const size_t rowB0 = (size_t)b * L_SEQ * 128 + 64 + nn;     // stride 128

  // prologue: stage chunk 0
  {
    const size_t rX = rowX0 + (size_t)grp * DINNER;
    const size_t rB = rowB0 + (size_t)grp * 128;
    float dv = dy[rX];
    float uv = x[rX];
    float bv = dbc[rB];
    float cv = dbc[rB + 32];
    *(float2*)&sDU[0][grp][nn][0] = make_float2(dv, uv);
    *(float2*)&sBC[0][grp][nn][0] = make_float2(bv, cv);
  }
  __syncthreads();

  float h = 0.f;

  for (int c = 0; c < L_SEQ / TCH; ++c) {
    const int cb = c & 1;
    float4 nxt;
    if (c < L_SEQ / TCH - 1) {  // issue next chunk's loads (latency hidden by compute)
      const size_t rX = rowX0 + (size_t)((c + 1) * TCH + grp) * DINNER;
      const size_t rB = rowB0 + (size_t)((c + 1) * TCH + grp) * 128;
      nxt.x = dy[rX];
      nxt.y = x[rX];
      nxt.z = dbc[rB];
      nxt.w = dbc[rB + 32];
    }

    const float* pDU = &sDU[cb][0][grp][0];
    const float* pBC = &sBC[cb][0][nn][0];
    float yv = 0.f;
#pragma unroll
    for (int t = 0; t < TCH; ++t) {
      const float2 du = *(const float2*)(pDU + t * 64);  // broadcast per group
      const float2 bc = *(const float2*)(pBC + t * 64);  // per-state
      const float dA = __expf(du.x * An);
      h = fmaf(dA, h, du.x * du.y * bc.x);
      float p = h * bc.y;
      p = red32(p);                 // sum over 32 states
      p = fmaf(du.y, Dd, p);        // + u*D
      yv = (nn == t) ? p : yv;      // collect y(t) into lane t
    }
    sY[nn][grp] = yv;  // [t][channel], padded
    __syncthreads();

    // coalesced y store: thread (t-local=grp, channel=nn)
    dy[(size_t)(b * L_SEQ + c * TCH + grp) * DINNER + d0 + nn] = sY[grp][nn];

    if (c < L_SEQ / TCH - 1) {
      *(float2*)&sDU[cb ^ 1][grp][nn][0] = make_float2(nxt.x, nxt.y);
      *(float2*)&sBC[cb ^ 1][grp][nn][0] = make_float2(nxt.z, nxt.w);
    }
    __syncthreads();
  }
}

extern "C" void kernel_launch(void* const* d_in, const int* in_sizes, int n_in,
                              void* d_out, int out_size, void* d_ws, size_t ws_size,
                              hipStream_t stream) {
  const float* x    = (const float*)d_in[0];
  const float* Wbc  = (const float*)d_in[2];
  const float* Wdt  = (const float*)d_in[3];
  const float* bdt  = (const float*)d_in[4];
  const float* Alog = (const float*)d_in[5];
  const float* Dpar = (const float*)d_in[6];
  float* dy  = (float*)d_out;
  float* dbc = (float*)d_ws;  // 8192*128 f32 = 4 MB

  hipLaunchKernelGGL(k_dbc, dim3(NROWS / 32), dim3(256), 0, stream, x, Wbc, dbc);
  hipLaunchKernelGGL(k_dt, dim3(DINNER / 128, NROWS / 16), dim3(256), 0, stream,
                     dbc, Wdt, bdt, dy);
  hipLaunchKernelGGL(k_scan, dim3(BSZ * DINNER / 32), dim3(1024), 0, stream,
                     x, dbc, Alog, Dpar, dy);
}